// Round 1
// baseline (1370.049 us; speedup 1.0000x reference)
//
#include <hip/hip_runtime.h>

typedef __attribute__((ext_vector_type(8))) short bf16x8;
typedef __attribute__((ext_vector_type(4))) float f32x4;
typedef __attribute__((ext_vector_type(4))) unsigned short us4;

#define NB 32
#define NT 512
#define NC 1024
#define NH 16
#define ND 64
#define NM (NB*NT)   /* 16384 rows */
#define N3 (3*NC)    /* 3072 */

__device__ __forceinline__ unsigned short f2bf(float f) {
  union { float f; unsigned int u; } v; v.f = f;
  unsigned int u = v.u;
  return (unsigned short)((u + 0x7FFFu + ((u >> 16) & 1u)) >> 16);
}
__device__ __forceinline__ float bf2f(unsigned short h) {
  union { float f; unsigned int u; } v; v.u = ((unsigned int)h) << 16;
  return v.f;
}

// C[M][N] = A[M][K] * W[N][K]^T + bias, via 3-term bf16-split MFMA.
// EPI 0: scatter to Q/K/V [NB][NH][NT][ND] (per-head interleaved qkv layout).
// EPI 1: plain row-major out [M][N].
template<int EPI>
__global__ __launch_bounds__(256, 2)
void gemm_split(const float* __restrict__ A, const float* __restrict__ W,
                const float* __restrict__ bias,
                float* __restrict__ O0, float* __restrict__ O1,
                float* __restrict__ O2, int K, int N)
{
  __shared__ unsigned short sAh[128*32], sAl[128*32], sBh[128*32], sBl[128*32];
  const int tid  = threadIdx.x;
  const int lane = tid & 63;
  const int wave = tid >> 6;
  const int wr = wave >> 1, wc = wave & 1;
  const int l15 = lane & 15, g = lane >> 4;
  const int tb = blockIdx.x, ob = blockIdx.y;

  const f32x4 zero = {0.f, 0.f, 0.f, 0.f};
  f32x4 acc[4][4];
#pragma unroll
  for (int i = 0; i < 4; ++i)
#pragma unroll
    for (int j = 0; j < 4; ++j) acc[i][j] = zero;

  const int srow = tid >> 3;        // 0..31
  const int scol = (tid & 7) << 2;  // 0,4,...,28

  const float* Ap = A + (size_t)(tb*128 + srow) * K + scol;
  const float* Wp = W + (size_t)(ob*128 + srow) * K + scol;

  for (int k0 = 0; k0 < K; k0 += 32) {
#pragma unroll
    for (int rr = 0; rr < 128; rr += 32) {
      const int r  = srow + rr;
      // swizzled byte offset: 64B rows, XOR 16B-slot bits with (r&3)
      const int wb = (r << 6) + (((scol << 1)) ^ ((r & 3) << 4));
      f32x4 va = *(const f32x4*)(Ap + (size_t)rr * K + k0);
      us4 h, lo;
#pragma unroll
      for (int i = 0; i < 4; ++i) {
        unsigned short hh = f2bf(va[i]);
        h[i]  = hh;
        lo[i] = f2bf(va[i] - bf2f(hh));
      }
      *(us4*)((char*)sAh + wb) = h;
      *(us4*)((char*)sAl + wb) = lo;
      f32x4 vb = *(const f32x4*)(Wp + (size_t)rr * K + k0);
#pragma unroll
      for (int i = 0; i < 4; ++i) {
        unsigned short hh = f2bf(vb[i]);
        h[i]  = hh;
        lo[i] = f2bf(vb[i] - bf2f(hh));
      }
      *(us4*)((char*)sBh + wb) = h;
      *(us4*)((char*)sBl + wb) = lo;
    }
    __syncthreads();

    bf16x8 bhf[4], blf[4];
#pragma unroll
    for (int nj = 0; nj < 4; ++nj) {
      const int r  = wc*64 + nj*16 + l15;
      const int rb = (r << 6) + (((g << 4)) ^ ((r & 3) << 4));
      bhf[nj] = *(const bf16x8*)((const char*)sBh + rb);
      blf[nj] = *(const bf16x8*)((const char*)sBl + rb);
    }
#pragma unroll
    for (int mi = 0; mi < 4; ++mi) {
      const int r  = wr*64 + mi*16 + l15;
      const int rb = (r << 6) + (((g << 4)) ^ ((r & 3) << 4));
      bf16x8 ah = *(const bf16x8*)((const char*)sAh + rb);
      bf16x8 al = *(const bf16x8*)((const char*)sAl + rb);
#pragma unroll
      for (int nj = 0; nj < 4; ++nj) {
        acc[mi][nj] = __builtin_amdgcn_mfma_f32_16x16x32_bf16(ah, bhf[nj], acc[mi][nj], 0, 0, 0);
        acc[mi][nj] = __builtin_amdgcn_mfma_f32_16x16x32_bf16(ah, blf[nj], acc[mi][nj], 0, 0, 0);
        acc[mi][nj] = __builtin_amdgcn_mfma_f32_16x16x32_bf16(al, bhf[nj], acc[mi][nj], 0, 0, 0);
      }
    }
    __syncthreads();
  }

  // epilogue: C/D layout (m89-verified): col = lane&15, row = (lane>>4)*4 + reg
#pragma unroll
  for (int mi = 0; mi < 4; ++mi) {
#pragma unroll
    for (int nj = 0; nj < 4; ++nj) {
#pragma unroll
      for (int r = 0; r < 4; ++r) {
        const int trow = tb*128 + wr*64 + mi*16 + g*4 + r;
        const int ocol = ob*128 + wc*64 + nj*16 + l15;
        const float val = acc[mi][nj][r] + bias[ocol];
        if (EPI == 0) {
          const int h  = ocol / 192;          // head
          const int rr = ocol - h*192;        // 0..191: q|k|v
          const int b  = trow >> 9, tt = trow & 511;
          const size_t base = (((size_t)(b*NH + h))*NT + tt)*ND;
          if (rr < 64)       O0[base + rr] = val;
          else if (rr < 128) O1[base + rr - 64] = val;
          else               O2[base + rr - 128] = val;
        } else {
          O0[(size_t)trow * N + ocol] = val;
        }
      }
    }
  }
}

// Vector fp32 causal attention with online softmax.
// Q/K/V: [NB*NH][NT][ND] fp32. One thread = one q row. grid (NB*NH, 2).
__global__ __launch_bounds__(256, 2)
void attn_vec(const float* __restrict__ Q, const float* __restrict__ Kb,
              const float* __restrict__ Vb, float* __restrict__ Y)
{
  __shared__ float sk[64*64];
  __shared__ float sv[64*64];
  const int tid  = threadIdx.x;
  const int bh   = blockIdx.x;           // b*NH + h
  const int half = blockIdx.y;
  const int qr   = half*256 + tid;

  const float* qp = Q + ((size_t)bh*NT + qr)*ND;
  const f32x4 zero = {0.f, 0.f, 0.f, 0.f};
  f32x4 q[16], y[16];
#pragma unroll
  for (int i = 0; i < 16; ++i) {
    q[i] = *(const f32x4*)(qp + i*4);
    y[i] = zero;
  }
  float m = -1e30f, l = 0.0f;
  const int ntiles = 4 + half*4;

  for (int kt = 0; kt < ntiles; ++kt) {
    __syncthreads();
#pragma unroll
    for (int i = 0; i < 4; ++i) {
      const int e   = i*256 + tid;        // float4 index 0..1023
      const int row = e >> 4;
      const int c4  = (e & 15) << 2;
      const size_t src = ((size_t)bh*NT + kt*64 + row)*ND + c4;
      *(f32x4*)&sk[(row << 6) + c4] = *(const f32x4*)(Kb + src);
      *(f32x4*)&sv[(row << 6) + c4] = *(const f32x4*)(Vb + src);
    }
    __syncthreads();

    int nk = qr - (kt << 6) + 1;
    if (nk > 64) nk = 64;
    for (int k = 0; k < nk; ++k) {
      const f32x4* kr = (const f32x4*)&sk[k << 6];
      f32x4 dpa = zero, dpb = zero;
#pragma unroll
      for (int i = 0; i < 8; ++i) {
        dpa += q[i]   * kr[i];
        dpb += q[i+8] * kr[i+8];
      }
      const f32x4 dp = dpa + dpb;
      const float s = (dp[0] + dp[1] + dp[2] + dp[3]) * 0.125f;

      // branchless online-softmax update (new-max handled via corr)
      const bool  nm   = (s > m);
      const float mnew = nm ? s : m;
      const float p    = __expf(s - mnew);
      const float corr = nm ? __expf(m - s) : 1.0f;
      m = mnew;
      l = l * corr + p;
      const f32x4* vr = (const f32x4*)&sv[k << 6];
#pragma unroll
      for (int i = 0; i < 16; ++i)
        y[i] = y[i] * corr + p * vr[i];
    }
  }

  const float inv = 1.0f / l;
  const int b = bh >> 4, h = bh & 15;
  float* yp = Y + ((size_t)(b*NT + qr))*NC + h*ND;
#pragma unroll
  for (int i = 0; i < 16; ++i) {
    f32x4 o = y[i] * inv;
    *(f32x4*)(yp + i*4) = o;
  }
}

extern "C" void kernel_launch(void* const* d_in, const int* in_sizes, int n_in,
                              void* d_out, int out_size, void* d_ws, size_t ws_size,
                              hipStream_t stream)
{
  const float* x    = (const float*)d_in[0];
  const float* Wqkv = (const float*)d_in[1];
  const float* bqkv = (const float*)d_in[2];
  const float* Wout = (const float*)d_in[3];
  const float* bout = (const float*)d_in[4];
  float* out = (float*)d_out;

  const size_t perArr = (size_t)NB*NH*NT*ND;   // 16,777,216 floats
  float* Qw = (float*)d_ws;
  float* Kw = Qw + perArr;
  float* Vw = Kw + perArr;
  float* Yw = Vw + perArr;                     // [NM][NC] fp32

  // 1) qkv projection + per-head scatter
  gemm_split<0><<<dim3(NM/128, N3/128), 256, 0, stream>>>(
      x, Wqkv, bqkv, Qw, Kw, Vw, NC, N3);
  // 2) causal attention, online softmax
  attn_vec<<<dim3(NB*NH, 2), 256, 0, stream>>>(Qw, Kw, Vw, Yw);
  // 3) output projection
  gemm_split<1><<<dim3(NM/128, NC/128), 256, 0, stream>>>(
      Yw, Wout, bout, out, nullptr, nullptr, NC, NC);
}